// Round 1
// baseline (631.829 us; speedup 1.0000x reference)
//
#include <hip/hip_runtime.h>
#include <math.h>

// FrankWolfePolicyImprovement: 4096 independent problems (B=32,S=128), n=64 acts,
// m=32 constraints (28 hard + 4 soft). Pipeline: anchor QP (ADMM 80 it, d=68) ->
// tanh MLP gradient -> row-normalized LMO QP (ADMM 80 it, d=64) -> blend.
// One wave (64 threads) per problem. S^-1 rows live in VGPRs (lane t = row t),
// computed by rotating-column Gauss-Jordan (readlane-based, no dynamic VGPR idx).

constexpr float SIG  = 1e-6f;
constexpr float C2   = 1.0f / (4.0f + 1e-6f);   // 1/(4+sigma): slack Schur diag
constexpr int   ITRS = 80;

__device__ __forceinline__ float rl(float v, int lane) {
  return __uint_as_float(__builtin_amdgcn_readlane(__float_as_uint(v), lane));
}

// In-place Gauss-Jordan inverse of SPD matrix, column layout with rotation:
// on entry lane j holds Cm[i] = S[i][j]; on exit Cm[i] = Sinv[i][j] (= row j, symmetric).
// Pivot p's column is fetched via readlane (uniform SGPR lane index); the
// logical row-rotation is fused into the shifted write, so p-loop stays rolled.
__device__ __forceinline__ void gj_invert(float (&Cm)[64], int t) {
  for (int p = 0; p < 64; ++p) {
    float piv = 1.0f / rl(Cm[0], p);
    bool  isP = (t == p);
    float sc  = Cm[0] * piv;
    float a    = isP ? (1.0f + piv) : sc;  // lane p: Cm[m]-Cm[m]*(1+piv) = -Cm[m]*piv
    float last = isP ? piv          : sc;  // new row-p entry -> slot 63
#pragma unroll
    for (int m = 1; m < 64; ++m) {
      float s = rl(Cm[m], p);              // pivot column element (lane p)
      Cm[m - 1] = fmaf(-s, a, Cm[m]);      // update + rotate-left in one write
    }
    Cm[63] = last;
  }
}

// ---------------- anchor QP ----------------
// w=[x(64),s(4)]; C rows: [I|0](64) [Ah|0](28) [As|-I](4) [0|I](4); M Schur-reduced.
__global__ __launch_bounds__(64) void anchor_kernel(
    const float* __restrict__ xraw, const float* __restrict__ A,
    const float* __restrict__ b, float* __restrict__ xfeas) {
  const int n = blockIdx.x, t = threadIdx.x;
  const float* Ap = A + (size_t)n * 2048;

  __shared__ __align__(16) float lsA[32 * 65];
  __shared__ __align__(16) float lst1[64];
  __shared__ __align__(16) float lsx[64];
  __shared__ __align__(16) float lsv2[32];
  __shared__ float lsv3[4], lsr2[4], lss[4];

  for (int k = 0; k < 32; ++k) lsA[k * 65 + t] = Ap[k * 64 + t];  // coalesced
  __syncthreads();

  const int r = t & 31, c0 = (t >> 5) << 5;
  float acol[32], arow[32];
#pragma unroll
  for (int k = 0; k < 32; ++k) acol[k] = lsA[k * 65 + t];        // A[k][t]
#pragma unroll
  for (int j = 0; j < 32; ++j) arow[j] = lsA[r * 65 + c0 + j];   // A[r][c0+j]

  // S column t: (2+sig)I + A^T A - C2 * As^T As  (As = rows 28..31)
  float Cm[64];
#pragma unroll
  for (int i = 0; i < 64; ++i) Cm[i] = 0.f;
  for (int k = 0; k < 32; ++k) {
    float w  = (k < 28) ? 1.0f : (1.0f - C2);
    float ak = w * lsA[k * 65 + t];
#pragma unroll
    for (int i = 0; i < 64; ++i) Cm[i] = fmaf(ak, lsA[k * 65 + i], Cm[i]);
  }
#pragma unroll
  for (int i = 0; i < 64; ++i) Cm[i] += (i == t) ? (2.0f + SIG) : 0.0f;

  gj_invert(Cm, t);  // Cm[j] = Sinv[t][j]

  const float xf = xraw[(size_t)n * 64 + t];
  const float bl = (t < 32) ? b[(size_t)n * 32 + t] : 0.f;

  float x_loc = 0.f, s_loc = 0.f;
  float z1 = 0.f, y1 = 0.f;                       // rows t: l=0,u=inf
  float z2 = (t < 32) ? fminf(0.f, bl) : 0.f;     // rows 64+t: l=-inf,u=b
  float y2 = 0.f;
  float z3 = 0.f, y3 = 0.f;                       // lanes 32..35: rows 96..99

  for (int it = 0; it < ITRS; ++it) {
    float v2 = z2 - y2;
    if (t < 32) lsv2[t] = v2;
    if (t >= 32 && t < 36) lsv3[t - 32] = z3 - y3;
    __syncthreads();

    // rhs x-part: sig*x + xf + v1 + A^T v2
    float r1 = fmaf(SIG, x_loc, xf) + (z1 - y1);
#pragma unroll
    for (int k = 0; k < 32; ++k) r1 = fmaf(acol[k], lsv2[k], r1);

    // rhs s-part (lanes 28..31): sig*s - v[92+i] + v[96+i]
    float r2loc = 0.f;
    if (t >= 28 && t < 32) {
      r2loc = fmaf(SIG, s_loc, lsv3[t - 28] - v2);
      lsr2[t - 28] = r2loc;
    }
    __syncthreads();

    // t1 = r1 + C2 * As^T r2
    float acc = 0.f;
#pragma unroll
    for (int i = 0; i < 4; ++i) acc = fmaf(acol[28 + i], lsr2[i], acc);
    lst1[t] = fmaf(C2, acc, r1);
    __syncthreads();

    // x = Sinv * t1
    float xn = 0.f;
#pragma unroll
    for (int j = 0; j < 64; ++j) xn = fmaf(Cm[j], lst1[j], xn);
    x_loc = xn;
    lsx[t] = xn;
    __syncthreads();

    // (A x)[r]: split halves + combine
    float pa = 0.f;
#pragma unroll
    for (int j = 0; j < 32; ++j) pa = fmaf(arow[j], lsx[c0 + j], pa);
    pa += __shfl_xor(pa, 32);

    // s = C2*(r2 + As x)  (lanes 28..31)
    if (t >= 28 && t < 32) {
      s_loc = C2 * (r2loc + pa);
      lss[t - 28] = s_loc;
    }
    __syncthreads();

    // z,y updates
    { float q1 = xn + y1; z1 = fmaxf(q1, 0.f); y1 = q1 - z1; }
    if (t < 32) {
      float Cx2 = pa - ((t >= 28) ? s_loc : 0.f);   // rows 92..95: As x - s
      float q2 = Cx2 + y2; z2 = fminf(q2, bl); y2 = q2 - z2;
    }
    if (t >= 32 && t < 36) {
      float q3 = lss[t - 32] + y3; z3 = fmaxf(q3, 0.f); y3 = q3 - z3;
    }
  }
  xfeas[(size_t)n * 64 + t] = x_loc;
}

// ---------------- W1 transpose (64x256 -> 256x64) ----------------
__global__ void w1t_kernel(const float* __restrict__ W1, float* __restrict__ W1T) {
  int idx = blockIdx.x * 256 + threadIdx.x;
  if (idx < 64 * 256) {
    int c = idx >> 6, j = idx & 63;
    W1T[idx] = W1[j * 256 + c];
  }
}

// ---------------- MLP gradient: g = ((1-tanh(xW1)^2)*w2) @ W1^T ----------------
__global__ __launch_bounds__(64) void mlp_kernel(
    const float* __restrict__ xfeas, const float* __restrict__ W1,
    const float* __restrict__ W1T, const float* __restrict__ w2,
    float* __restrict__ g) {
  const int n = blockIdx.x, t = threadIdx.x;
  __shared__ __align__(16) float lsu[256];
  const float xl = xfeas[(size_t)n * 64 + t];
  const float4* W1v = (const float4*)W1;
  float4 acc = make_float4(0.f, 0.f, 0.f, 0.f);
  for (int j = 0; j < 64; ++j) {
    float xj = rl(xl, j);
    float4 w = W1v[j * 64 + t];       // W1[j][4t..4t+3], coalesced
    acc.x = fmaf(xj, w.x, acc.x);
    acc.y = fmaf(xj, w.y, acc.y);
    acc.z = fmaf(xj, w.z, acc.z);
    acc.w = fmaf(xj, w.w, acc.w);
  }
  float4 wv = ((const float4*)w2)[t];
  float hx;
  float u0, u1, u2, u3;
  hx = tanhf(acc.x); u0 = (1.f - hx * hx) * wv.x;
  hx = tanhf(acc.y); u1 = (1.f - hx * hx) * wv.y;
  hx = tanhf(acc.z); u2 = (1.f - hx * hx) * wv.z;
  hx = tanhf(acc.w); u3 = (1.f - hx * hx) * wv.w;
  ((float4*)lsu)[t] = make_float4(u0, u1, u2, u3);
  __syncthreads();
  float acc2 = 0.f;
  for (int c = 0; c < 256; ++c) acc2 = fmaf(W1T[c * 64 + t], lsu[c], acc2);
  g[(size_t)n * 64 + t] = acc2;
}

// ---------------- LMO QP ----------------
// min eps/2||c||^2 - g'c st c>=0, An c <= bn ; M = (1+eps+sig)I + An^T An.
__global__ __launch_bounds__(64) void lmo_kernel(
    const float* __restrict__ A, const float* __restrict__ b,
    const float* __restrict__ g, const float* __restrict__ xfeas,
    float* __restrict__ out) {
  const int n = blockIdx.x, t = threadIdx.x;
  const float* Ap = A + (size_t)n * 2048;

  __shared__ __align__(16) float lsA[32 * 65];
  __shared__ __align__(16) float lst1[64];
  __shared__ __align__(16) float lsx[64];
  __shared__ __align__(16) float lsv2[32];
  __shared__ float lsrn[32];

  for (int k = 0; k < 32; ++k) lsA[k * 65 + t] = Ap[k * 64 + t];
  __syncthreads();

  const int r = t & 31, c0 = (t >> 5) << 5;

  // row norms
  float pr = 0.f;
#pragma unroll
  for (int j = 0; j < 32; ++j) { float v = lsA[r * 65 + c0 + j]; pr = fmaf(v, v, pr); }
  pr += __shfl_xor(pr, 32);
  if (t < 32) lsrn[t] = fmaxf(sqrtf(pr), 1e-12f);
  __syncthreads();

  // scale in place: An = A / rn
#pragma unroll
  for (int k = 0; k < 32; ++k) lsA[k * 65 + t] *= (1.0f / lsrn[k]);
  __syncthreads();

  const float bn = (t < 32) ? b[(size_t)n * 32 + t] / lsrn[t] : 0.f;

  float acol[32], arow[32];
#pragma unroll
  for (int k = 0; k < 32; ++k) acol[k] = lsA[k * 65 + t];
#pragma unroll
  for (int j = 0; j < 32; ++j) arow[j] = lsA[r * 65 + c0 + j];

  // M column t
  float Cm[64];
#pragma unroll
  for (int i = 0; i < 64; ++i) Cm[i] = 0.f;
  for (int k = 0; k < 32; ++k) {
    float ak = lsA[k * 65 + t];
#pragma unroll
    for (int i = 0; i < 64; ++i) Cm[i] = fmaf(ak, lsA[k * 65 + i], Cm[i]);
  }
#pragma unroll
  for (int i = 0; i < 64; ++i) Cm[i] += (i == t) ? (1.0f + 1e-4f + SIG) : 0.0f;

  gj_invert(Cm, t);

  const float gl = g[(size_t)n * 64 + t];
  float x_loc = 0.f, z1 = 0.f, y1 = 0.f;
  float z2 = (t < 32) ? fminf(0.f, bn) : 0.f;
  float y2 = 0.f;

  for (int it = 0; it < ITRS; ++it) {
    if (t < 32) lsv2[t] = z2 - y2;
    __syncthreads();
    // rhs = sig*x + g + v1 + An^T v2   (q = -g)
    float r1 = fmaf(SIG, x_loc, gl) + (z1 - y1);
#pragma unroll
    for (int k = 0; k < 32; ++k) r1 = fmaf(acol[k], lsv2[k], r1);
    lst1[t] = r1;
    __syncthreads();
    float xn = 0.f;
#pragma unroll
    for (int j = 0; j < 64; ++j) xn = fmaf(Cm[j], lst1[j], xn);
    x_loc = xn;
    lsx[t] = xn;
    __syncthreads();
    float pa = 0.f;
#pragma unroll
    for (int j = 0; j < 32; ++j) pa = fmaf(arow[j], lsx[c0 + j], pa);
    pa += __shfl_xor(pa, 32);
    { float q1 = xn + y1; z1 = fmaxf(q1, 0.f); y1 = q1 - z1; }
    if (t < 32) { float q2 = pa + y2; z2 = fminf(q2, bn); y2 = q2 - z2; }
  }
  out[(size_t)n * 64 + t] = fmaf(0.1f, x_loc, 0.9f * xfeas[(size_t)n * 64 + t]);
}

extern "C" void kernel_launch(void* const* d_in, const int* in_sizes, int n_in,
                              void* d_out, int out_size, void* d_ws, size_t ws_size,
                              hipStream_t stream) {
  const float* xraw = (const float*)d_in[0];  // [N,64]
  const float* A    = (const float*)d_in[1];  // [N,32,64]
  const float* b    = (const float*)d_in[2];  // [N,32]
  const float* W1   = (const float*)d_in[3];  // [64,256]
  const float* w2   = (const float*)d_in[4];  // [256]
  float* out = (float*)d_out;

  const int nprob = in_sizes[0] / 64;

  float* W1T   = (float*)d_ws;                // 16384 floats
  float* xfeas = W1T + 64 * 256;              // nprob*64
  float* g     = xfeas + (size_t)nprob * 64;  // nprob*64

  w1t_kernel<<<64, 256, 0, stream>>>(W1, W1T);
  anchor_kernel<<<nprob, 64, 0, stream>>>(xraw, A, b, xfeas);
  mlp_kernel<<<nprob, 64, 0, stream>>>(xfeas, W1, W1T, w2, g);
  lmo_kernel<<<nprob, 64, 0, stream>>>(A, b, g, xfeas, out);
}

// Round 2
// 581.090 us; speedup vs baseline: 1.0873x; 1.0873x over previous
//
#include <hip/hip_runtime.h>
#include <math.h>

// FrankWolfePolicyImprovement, fused: 4096 problems, one wave (64 lanes) each.
// Phases (single kernel, A resident in LDS throughout):
//   1. anchor QP  (Schur-reduced d=68 ADMM, 80 it, Sinv rows in VGPRs)
//   2. tanh MLP gradient
//   3. row-normalize A in LDS, LMO QP (d=64 ADMM, 80 it)
//   4. blend + store
// Register budget: Cm[64] + acol[32] + state ~= 120; __launch_bounds__(64,4)
// targets 128 regs -> 4 waves/SIMD = 16 waves/CU = all available work resident.
// LDS: A at stride 68 (rows 16B-aligned -> ds_read_b128) + 256-float scratch
// (ADMM vectors / MLP u-buffer overlaid) = 9728 B -> 16 blocks/CU.

constexpr float SIG  = 1e-6f;
constexpr float C2   = 1.0f / (4.0f + 1e-6f);   // 1/(4+sigma): slack Schur diag
constexpr int   ITRS = 80;
constexpr int   LDA  = 68;                       // LDS stride for A (16B-aligned rows)

__device__ __forceinline__ float rl(float v, int lane) {
  return __uint_as_float(__builtin_amdgcn_readlane(__float_as_uint(v), lane));
}

// In-place Gauss-Jordan inverse of SPD matrix, column layout with rotation:
// on entry lane j holds Cm[i] = S[i][j]; on exit Cm[i] = Sinv[i][j] (= row j, symmetric).
// Pivot column fetched via readlane (VALU pipe; LDS pipe is the scarcer resource here);
// logical row-rotation fused into the shifted write so the p-loop stays rolled.
__device__ __forceinline__ void gj_invert(float (&Cm)[64], int t) {
  for (int p = 0; p < 64; ++p) {
    float piv = 1.0f / rl(Cm[0], p);
    bool  isP = (t == p);
    float sc  = Cm[0] * piv;
    float a    = isP ? (1.0f + piv) : sc;
    float last = isP ? piv          : sc;
#pragma unroll
    for (int m = 1; m < 64; ++m) {
      float s = rl(Cm[m], p);
      Cm[m - 1] = fmaf(-s, a, Cm[m]);
    }
    Cm[63] = last;
  }
}

__global__ __launch_bounds__(64, 4) void fw_kernel(
    const float* __restrict__ xraw, const float* __restrict__ A,
    const float* __restrict__ b, const float* __restrict__ W1,
    const float* __restrict__ W1T, const float* __restrict__ w2,
    float* __restrict__ out) {
  const int n = blockIdx.x, t = threadIdx.x;
  const float* Ap = A + (size_t)n * 2048;

  __shared__ __align__(16) float lsA[32 * LDA];   // 8704 B
  __shared__ __align__(16) float sbuf[256];       // 1024 B, multi-purpose
  float* lst1 = sbuf;            // [64]  ADMM t1 / rhs
  float* lsx  = sbuf + 64;       // [64]  ADMM x broadcast
  float* lsv2 = sbuf + 128;      // [32]
  float* lsv3 = sbuf + 160;      // [4]
  float* lsr2 = sbuf + 164;      // [4]
  float* lss  = sbuf + 168;      // [4]
  float* lsrn = sbuf + 176;      // [32] row norms (LMO phase)
  // MLP phase reuses sbuf[0..255] as the u-vector.

  // ---- stage A into LDS (float4 both sides) ----
  const float4* Apv = (const float4*)Ap;
#pragma unroll
  for (int jj = 0; jj < 8; ++jj) {
    float4 a4 = Apv[t + 64 * jj];
    int k = (t >> 4) + 4 * jj;        // row
    int col = 4 * (t & 15);
    *((float4*)&lsA[k * LDA + col]) = a4;
  }
  __syncthreads();

  const int r = t & 31, c0 = (t >> 5) << 5;

  float acol[32];
#pragma unroll
  for (int k = 0; k < 32; ++k) acol[k] = lsA[k * LDA + t];   // A[k][t]

  // ================= anchor QP =================
  // S column t: (2+sig)I + A^T A - C2 * As^T As  (As = rows 28..31)
  float Cm[64];
#pragma unroll
  for (int i = 0; i < 64; ++i) Cm[i] = 0.f;
  for (int k = 0; k < 32; ++k) {
    float wk = (k < 28) ? 1.0f : (1.0f - C2);
    float ak = wk * acol[k];
#pragma unroll
    for (int ii = 0; ii < 16; ++ii) {
      float4 a4 = *((const float4*)&lsA[k * LDA + 4 * ii]);
      Cm[4 * ii + 0] = fmaf(ak, a4.x, Cm[4 * ii + 0]);
      Cm[4 * ii + 1] = fmaf(ak, a4.y, Cm[4 * ii + 1]);
      Cm[4 * ii + 2] = fmaf(ak, a4.z, Cm[4 * ii + 2]);
      Cm[4 * ii + 3] = fmaf(ak, a4.w, Cm[4 * ii + 3]);
    }
  }
#pragma unroll
  for (int i = 0; i < 64; ++i) Cm[i] += (i == t) ? (2.0f + SIG) : 0.0f;

  gj_invert(Cm, t);  // Cm[j] = Sinv[t][j]

  const float xf = xraw[(size_t)n * 64 + t];
  const float bl = (t < 32) ? b[(size_t)n * 32 + t] : 0.f;

  float x_loc = 0.f, s_loc = 0.f;
  float z1 = 0.f, y1 = 0.f;
  float z2 = (t < 32) ? fminf(0.f, bl) : 0.f;
  float y2 = 0.f;
  float z3 = 0.f, y3 = 0.f;

  for (int it = 0; it < ITRS; ++it) {
    float v2 = z2 - y2;
    if (t < 32) lsv2[t] = v2;
    if (t >= 32 && t < 36) lsv3[t - 32] = z3 - y3;
    __syncthreads();

    // rhs x-part: sig*x + xf + v1 + A^T v2
    float r1 = fmaf(SIG, x_loc, xf) + (z1 - y1);
#pragma unroll
    for (int kk = 0; kk < 8; ++kk) {
      float4 v4 = ((const float4*)lsv2)[kk];
      r1 = fmaf(acol[4 * kk + 0], v4.x, r1);
      r1 = fmaf(acol[4 * kk + 1], v4.y, r1);
      r1 = fmaf(acol[4 * kk + 2], v4.z, r1);
      r1 = fmaf(acol[4 * kk + 3], v4.w, r1);
    }

    // rhs s-part (lanes 28..31): sig*s - v[92+i] + v[96+i]
    float r2loc = 0.f;
    if (t >= 28 && t < 32) {
      r2loc = fmaf(SIG, s_loc, lsv3[t - 28] - v2);
      lsr2[t - 28] = r2loc;
    }
    __syncthreads();

    // t1 = r1 + C2 * As^T r2
    float acc = 0.f;
#pragma unroll
    for (int i = 0; i < 4; ++i) acc = fmaf(acol[28 + i], lsr2[i], acc);
    lst1[t] = fmaf(C2, acc, r1);
    __syncthreads();

    // x = Sinv * t1
    float xn = 0.f;
#pragma unroll
    for (int jj = 0; jj < 16; ++jj) {
      float4 t4 = ((const float4*)lst1)[jj];
      xn = fmaf(Cm[4 * jj + 0], t4.x, xn);
      xn = fmaf(Cm[4 * jj + 1], t4.y, xn);
      xn = fmaf(Cm[4 * jj + 2], t4.z, xn);
      xn = fmaf(Cm[4 * jj + 3], t4.w, xn);
    }
    x_loc = xn;
    lsx[t] = xn;
    __syncthreads();

    // (A x)[r]: split halves + combine
    float pa = 0.f;
#pragma unroll
    for (int jj = 0; jj < 8; ++jj) {
      float4 x4 = ((const float4*)(lsx + c0))[jj];
      float4 a4 = *((const float4*)&lsA[r * LDA + c0 + 4 * jj]);
      pa = fmaf(a4.x, x4.x, pa);
      pa = fmaf(a4.y, x4.y, pa);
      pa = fmaf(a4.z, x4.z, pa);
      pa = fmaf(a4.w, x4.w, pa);
    }
    pa += __shfl_xor(pa, 32);

    // s = C2*(r2 + As x)  (lanes 28..31)
    if (t >= 28 && t < 32) {
      s_loc = C2 * (r2loc + pa);
      lss[t - 28] = s_loc;
    }
    __syncthreads();

    { float q1 = xn + y1; z1 = fmaxf(q1, 0.f); y1 = q1 - z1; }
    if (t < 32) {
      float Cx2 = pa - ((t >= 28) ? s_loc : 0.f);
      float q2 = Cx2 + y2; z2 = fminf(q2, bl); y2 = q2 - z2;
    }
    if (t >= 32 && t < 36) {
      float q3 = lss[t - 32] + y3; z3 = fmaxf(q3, 0.f); y3 = q3 - z3;
    }
  }
  const float xfeas_r = x_loc;   // final lsx also holds x_feas

  // ================= MLP gradient =================
  __syncthreads();
  float4 hacc = make_float4(0.f, 0.f, 0.f, 0.f);
  const float4* W1v = (const float4*)W1;
#pragma unroll 4
  for (int j = 0; j < 64; ++j) {
    float xj = lsx[j];
    float4 w = W1v[j * 64 + t];
    hacc.x = fmaf(xj, w.x, hacc.x);
    hacc.y = fmaf(xj, w.y, hacc.y);
    hacc.z = fmaf(xj, w.z, hacc.z);
    hacc.w = fmaf(xj, w.w, hacc.w);
  }
  float4 wv = ((const float4*)w2)[t];
  float hx;
  float u0, u1, u2, u3;
  hx = tanhf(hacc.x); u0 = (1.f - hx * hx) * wv.x;
  hx = tanhf(hacc.y); u1 = (1.f - hx * hx) * wv.y;
  hx = tanhf(hacc.z); u2 = (1.f - hx * hx) * wv.z;
  hx = tanhf(hacc.w); u3 = (1.f - hx * hx) * wv.w;
  __syncthreads();                       // everyone done reading lsx
  ((float4*)sbuf)[t] = make_float4(u0, u1, u2, u3);   // sbuf = u[256]
  __syncthreads();
  float gl = 0.f;
#pragma unroll 8
  for (int c = 0; c < 256; ++c) gl = fmaf(W1T[c * 64 + t], sbuf[c], gl);
  __syncthreads();                       // before lsrn overwrites sbuf

  // ================= normalize A in LDS =================
  float pr = 0.f;
#pragma unroll
  for (int jj = 0; jj < 8; ++jj) {
    float4 a4 = *((const float4*)&lsA[r * LDA + c0 + 4 * jj]);
    pr = fmaf(a4.x, a4.x, pr);
    pr = fmaf(a4.y, a4.y, pr);
    pr = fmaf(a4.z, a4.z, pr);
    pr = fmaf(a4.w, a4.w, pr);
  }
  pr += __shfl_xor(pr, 32);
  if (t < 32) lsrn[t] = fmaxf(sqrtf(pr), 1e-12f);
  __syncthreads();
#pragma unroll
  for (int k = 0; k < 32; ++k) lsA[k * LDA + t] *= (1.0f / lsrn[k]);
  const float bn = (t < 32) ? bl / lsrn[t] : 0.f;
  __syncthreads();

  // ================= LMO QP =================
#pragma unroll
  for (int k = 0; k < 32; ++k) acol[k] = lsA[k * LDA + t];   // normalized cols

#pragma unroll
  for (int i = 0; i < 64; ++i) Cm[i] = 0.f;
  for (int k = 0; k < 32; ++k) {
    float ak = acol[k];
#pragma unroll
    for (int ii = 0; ii < 16; ++ii) {
      float4 a4 = *((const float4*)&lsA[k * LDA + 4 * ii]);
      Cm[4 * ii + 0] = fmaf(ak, a4.x, Cm[4 * ii + 0]);
      Cm[4 * ii + 1] = fmaf(ak, a4.y, Cm[4 * ii + 1]);
      Cm[4 * ii + 2] = fmaf(ak, a4.z, Cm[4 * ii + 2]);
      Cm[4 * ii + 3] = fmaf(ak, a4.w, Cm[4 * ii + 3]);
    }
  }
#pragma unroll
  for (int i = 0; i < 64; ++i) Cm[i] += (i == t) ? (1.0f + 1e-4f + SIG) : 0.0f;

  gj_invert(Cm, t);

  x_loc = 0.f; z1 = 0.f; y1 = 0.f;
  z2 = (t < 32) ? fminf(0.f, bn) : 0.f;
  y2 = 0.f;

  for (int it = 0; it < ITRS; ++it) {
    if (t < 32) lsv2[t] = z2 - y2;
    __syncthreads();
    float r1 = fmaf(SIG, x_loc, gl) + (z1 - y1);
#pragma unroll
    for (int kk = 0; kk < 8; ++kk) {
      float4 v4 = ((const float4*)lsv2)[kk];
      r1 = fmaf(acol[4 * kk + 0], v4.x, r1);
      r1 = fmaf(acol[4 * kk + 1], v4.y, r1);
      r1 = fmaf(acol[4 * kk + 2], v4.z, r1);
      r1 = fmaf(acol[4 * kk + 3], v4.w, r1);
    }
    lst1[t] = r1;
    __syncthreads();
    float xn = 0.f;
#pragma unroll
    for (int jj = 0; jj < 16; ++jj) {
      float4 t4 = ((const float4*)lst1)[jj];
      xn = fmaf(Cm[4 * jj + 0], t4.x, xn);
      xn = fmaf(Cm[4 * jj + 1], t4.y, xn);
      xn = fmaf(Cm[4 * jj + 2], t4.z, xn);
      xn = fmaf(Cm[4 * jj + 3], t4.w, xn);
    }
    x_loc = xn;
    lsx[t] = xn;
    __syncthreads();
    float pa = 0.f;
#pragma unroll
    for (int jj = 0; jj < 8; ++jj) {
      float4 x4 = ((const float4*)(lsx + c0))[jj];
      float4 a4 = *((const float4*)&lsA[r * LDA + c0 + 4 * jj]);
      pa = fmaf(a4.x, x4.x, pa);
      pa = fmaf(a4.y, x4.y, pa);
      pa = fmaf(a4.z, x4.z, pa);
      pa = fmaf(a4.w, x4.w, pa);
    }
    pa += __shfl_xor(pa, 32);
    { float q1 = xn + y1; z1 = fmaxf(q1, 0.f); y1 = q1 - z1; }
    if (t < 32) { float q2 = pa + y2; z2 = fminf(q2, bn); y2 = q2 - z2; }
    __syncthreads();
  }

  out[(size_t)n * 64 + t] = fmaf(0.1f, x_loc, 0.9f * xfeas_r);
}

// ---------------- W1 transpose (64x256 -> 256x64), once ----------------
__global__ void w1t_kernel(const float* __restrict__ W1, float* __restrict__ W1T) {
  int idx = blockIdx.x * 256 + threadIdx.x;
  if (idx < 64 * 256) {
    int c = idx >> 6, j = idx & 63;
    W1T[idx] = W1[j * 256 + c];
  }
}

extern "C" void kernel_launch(void* const* d_in, const int* in_sizes, int n_in,
                              void* d_out, int out_size, void* d_ws, size_t ws_size,
                              hipStream_t stream) {
  const float* xraw = (const float*)d_in[0];  // [N,64]
  const float* A    = (const float*)d_in[1];  // [N,32,64]
  const float* b    = (const float*)d_in[2];  // [N,32]
  const float* W1   = (const float*)d_in[3];  // [64,256]
  const float* w2   = (const float*)d_in[4];  // [256]
  float* out = (float*)d_out;

  const int nprob = in_sizes[0] / 64;
  float* W1T = (float*)d_ws;                  // 16384 floats

  w1t_kernel<<<64, 256, 0, stream>>>(W1, W1T);
  fw_kernel<<<nprob, 64, 0, stream>>>(xraw, A, b, W1, W1T, w2, out);
}